// Round 1
// baseline (79.210 us; speedup 1.0000x reference)
//
#include <hip/hip_runtime.h>

// Problem constants (match reference file).
#define BB      4
#define LL      4096
#define DD      8
#define KMAX    64
#define NCODES  256   // 2^D

// ---------------------------------------------------------------------------
// Kernel A: pack sign bits of key_up into one 8-bit code per (b, l).
// ---------------------------------------------------------------------------
__global__ void pack_key_codes(const float* __restrict__ key_up,
                               int* __restrict__ k_codes) {
    int idx = blockIdx.x * blockDim.x + threadIdx.x;   // 0 .. B*L-1
    if (idx >= BB * LL) return;
    const float4* p = reinterpret_cast<const float4*>(key_up + (size_t)idx * DD);
    float4 a = p[0];
    float4 b = p[1];
    int code = ((int)(a.x > 0.f))
             | ((int)(a.y > 0.f) << 1)
             | ((int)(a.z > 0.f) << 2)
             | ((int)(a.w > 0.f) << 3)
             | ((int)(b.x > 0.f) << 4)
             | ((int)(b.y > 0.f) << 5)
             | ((int)(b.z > 0.f) << 6)
             | ((int)(b.w > 0.f) << 7);
    k_codes[idx] = code;
}

// ---------------------------------------------------------------------------
// Kernel B: one wave per (batch, code). Scan the 4096 key codes, collect the
// first <=64 matching key indices (ascending) via ballot + prefix popcount,
// then emit the final answer row: (64 - m) leading -1 pads, then the m
// ascending match indices. res is [B][256][64] int32.
// ---------------------------------------------------------------------------
__global__ void build_res(const int* __restrict__ k_codes,
                          int* __restrict__ res) {
    __shared__ int buf[4][KMAX];                 // 4 waves per 256-thread block
    const int wslot = threadIdx.x >> 6;
    const int lane  = threadIdx.x & 63;
    const int wid   = blockIdx.x * 4 + wslot;    // 0 .. B*256-1
    const int b     = wid >> 8;
    const int c     = wid & (NCODES - 1);
    const int* codes = k_codes + b * LL;

    int found = 0;                               // wave-uniform running count
    for (int base = 0; base < LL; base += 64) {
        if (found >= KMAX) break;                // uniform early exit
        int j = base + lane;
        bool m = (codes[j] == c);
        unsigned long long mask = __ballot(m);
        if (m) {
            int rank = found + (int)__popcll(mask & ((1ull << lane) - 1ull));
            if (rank < KMAX) buf[wslot][rank] = j;   // within-wave LDS, lockstep
        }
        found += (int)__popcll(mask);
    }
    int mcount = found < KMAX ? found : KMAX;
    int pad    = KMAX - mcount;
    int val    = (lane < pad) ? -1 : buf[wslot][lane - pad];
    res[((size_t)b * NCODES + c) * KMAX + lane] = val;
}

// ---------------------------------------------------------------------------
// Kernel C: one wave per query row. Compute the query's code from a ballot of
// its 8 sign bits (lanes 0-7 contribute bits 0-7; lanes 8+ replicate), then
// copy the precomputed 64-int row to the output (coalesced 256B per wave).
// ---------------------------------------------------------------------------
__global__ void gather_out(const float* __restrict__ query_up,
                           const int* __restrict__ res,
                           int* __restrict__ out) {
    int tid  = blockIdx.x * blockDim.x + threadIdx.x;  // 0 .. B*L*64-1
    int q    = tid >> 6;                               // query index 0 .. B*L-1
    int lane = threadIdx.x & 63;
    if (q >= BB * LL) return;
    int b = q >> 12;                                   // / L
    float x = query_up[(size_t)q * DD + (lane & 7)];
    unsigned long long mask = __ballot(x > 0.f);
    int code = (int)(mask & 0xffull);                  // bits 0-7 = dims 0-7
    out[tid] = res[((size_t)b * NCODES + code) * KMAX + lane];
}

// ---------------------------------------------------------------------------
extern "C" void kernel_launch(void* const* d_in, const int* in_sizes, int n_in,
                              void* d_out, int out_size, void* d_ws, size_t ws_size,
                              hipStream_t stream) {
    const float* query_up = (const float*)d_in[0];   // [B, L, D] f32
    const float* key_up   = (const float*)d_in[1];   // [B, L, D] f32
    // d_in[2] = head_idx, unused by the reference math.

    int* out     = (int*)d_out;                          // [B, L, KMAX] int32
    int* k_codes = (int*)d_ws;                           // B*L ints = 64 KB
    int* res     = (int*)((char*)d_ws + (size_t)BB * LL * sizeof(int)); // 256 KB

    // A: key codes
    pack_key_codes<<<(BB * LL + 255) / 256, 256, 0, stream>>>(key_up, k_codes);
    // B: one wave per (b, code): 4*256 waves / 4 waves-per-block = 256 blocks
    build_res<<<(BB * NCODES) / 4, 256, 0, stream>>>(k_codes, res);
    // C: one wave per query row
    gather_out<<<(BB * LL * KMAX) / 256, 256, 0, stream>>>(query_up, res, out);
}

// Round 3
// 65.507 us; speedup vs baseline: 1.2092x; 1.2092x over previous
//
#include <hip/hip_runtime.h>

// Problem constants (match reference file).
#define BB      4
#define LL      4096
#define DD      8
#define KMAX    64
#define NCODES  256   // 2^D

// ---------------------------------------------------------------------------
// Kernel 1 (fused pack + build): grid = B*16 blocks of 1024 threads.
// Block (b, g): packs batch b's 4096 key codes into LDS, then its 16 waves
// each build the answer row for one code c = g*16 + w:
// the first <=64 ascending key indices with that code, left-padded with -1.
// res is [B][256][64] int32 in d_ws.
// ---------------------------------------------------------------------------
__global__ void __launch_bounds__(1024)
build_res(const float* __restrict__ key_up, int* __restrict__ res) {
    __shared__ int scodes[LL];          // 16 KB
    __shared__ int sbuf[16][KMAX];      // 4 KB

    const int b = blockIdx.x >> 4;          // batch
    const int g = blockIdx.x & 15;          // code group (16 codes)
    const int t = threadIdx.x;

    // --- pack: each thread packs 4 keys ---
    const float4* kp = reinterpret_cast<const float4*>(key_up + (size_t)b * LL * DD);
#pragma unroll
    for (int j = 0; j < 4; ++j) {
        int k = t + j * 1024;
        float4 a = kp[k * 2];
        float4 c4 = kp[k * 2 + 1];
        int code = ((int)(a.x > 0.f))
                 | ((int)(a.y > 0.f) << 1)
                 | ((int)(a.z > 0.f) << 2)
                 | ((int)(a.w > 0.f) << 3)
                 | ((int)(c4.x > 0.f) << 4)
                 | ((int)(c4.y > 0.f) << 5)
                 | ((int)(c4.z > 0.f) << 6)
                 | ((int)(c4.w > 0.f) << 7);
        scodes[k] = code;
    }
    __syncthreads();

    // --- build: wave w handles code c ---
    const int w    = t >> 6;
    const int lane = t & 63;
    const int c    = g * 16 + w;

    // hoist all 64 LDS reads into registers: no serial latency chain
    int v[64];
#pragma unroll
    for (int i = 0; i < 64; ++i) v[i] = scodes[i * 64 + lane];

    const unsigned long long prefix = (1ull << lane) - 1ull;
    int found = 0;
#pragma unroll
    for (int i = 0; i < 64; ++i) {
        bool m = (v[i] == c);
        unsigned long long mask = __ballot(m);
        if (m) {
            int rank = found + (int)__popcll(mask & prefix);
            if (rank < KMAX) sbuf[w][rank] = i * 64 + lane;
        }
        found += (int)__popcll(mask);
    }
    int mcount = found < KMAX ? found : KMAX;
    int pad    = KMAX - mcount;
    int val    = (lane < pad) ? -1 : sbuf[w][lane - pad];
    res[((size_t)b * NCODES + c) * KMAX + lane] = val;
}

// ---------------------------------------------------------------------------
// Kernel 2: each wave handles 4 query rows. One ballot produces all 4 codes
// (16-lane nibbles of the 64-bit mask); each lane moves 16 B (int4).
// ---------------------------------------------------------------------------
__global__ void gather_out(const float* __restrict__ query_up,
                           const int* __restrict__ res,
                           int* __restrict__ out) {
    int tid  = blockIdx.x * blockDim.x + threadIdx.x;   // 0 .. B*L*16-1
    int lane = threadIdx.x & 63;
    int wq   = tid >> 6;                 // wave id: 4 queries per wave
    int myq  = wq * 4 + (lane >> 4);     // this lane's query row
    int b    = myq >> 12;                // / L
    float x  = query_up[(size_t)myq * DD + (lane & 7)];
    unsigned long long mask = __ballot(x > 0.f);
    int code = (int)((mask >> ((lane >> 4) << 4)) & 0xffull);
    const int4* src = reinterpret_cast<const int4*>(res + ((size_t)b * NCODES + code) * KMAX);
    int4 vv = src[lane & 15];
    reinterpret_cast<int4*>(out)[(size_t)myq * 16 + (lane & 15)] = vv;
}

// ---------------------------------------------------------------------------
extern "C" void kernel_launch(void* const* d_in, const int* in_sizes, int n_in,
                              void* d_out, int out_size, void* d_ws, size_t ws_size,
                              hipStream_t stream) {
    const float* query_up = (const float*)d_in[0];   // [B, L, D] f32
    const float* key_up   = (const float*)d_in[1];   // [B, L, D] f32
    // d_in[2] = head_idx, unused by the reference math.

    int* out = (int*)d_out;        // [B, L, KMAX] int32
    int* res = (int*)d_ws;         // [B][256][64] int32 = 256 KB

    build_res<<<BB * 16, 1024, 0, stream>>>(key_up, res);
    gather_out<<<(BB * LL * 16) / 256, 256, 0, stream>>>(query_up, res, out);
}